// Round 1
// baseline (595.414 us; speedup 1.0000x reference)
//
#include <hip/hip_runtime.h>

// ProjectBEV: expand range-image coords (B,H,W,CK,2) into COO sparse-tensor
// index/value arrays, flattened float32 in return order:
//   [0, 6N)        presence_indices [N,6]  = [b, qx, qy, c, h, w]
//   [6N, 7N)       presence_vals    [N]    = 1
//   [7N, 21N)      position_indices [2N,7] = [b, qx, qy, c, h, w, d]
//   [21N, 23N)     position_vals    [2N]   = scaled_xy flat
// n ordered as (B, CK, H, W); input laid out (B, H, W, CK, 2).
//
// R3: position row-pair = [E, 0, E, 1] where E = presence row [b,qx,qy,c,h,w].
// So stage ONLY E (18 KB vs 42 KB): presence drain is a linear float4 copy of
// the staged layout, position drain gathers per-element from E via arithmetic
// LDS addressing (k mod 7) with a select for the d-columns (k==6 -> 0,
// k==13 -> 1). Removes the 42 KB row-pair staging, the 18 KB restage and two
// of the three barriers; LDS 18 KB -> 8 blocks/CU (full 32-wave occupancy) so
// the coalesced float4 store streams never convoy-stall on stage/barrier.

#define BB 16
#define HH 64
#define WW 2048
#define CKK 3
#define NN (BB * CKK * HH * WW)   // 6,291,456
#define SEG 256                    // w's per block
#define NBLK (BB * HH * (WW / SEG))  // 8192

__global__ __launch_bounds__(256) void ProjectBEV_kernel(
    const float* __restrict__ in, float* __restrict__ out) {
    // E staging: 3 chunks x 256 rows x 6 floats = 4608 floats (18 KB).
    // +8 pad: position gather may form address 6*255+6 at the last row of the
    // last chunk (value is select-overridden, but the read must be in-bounds).
    __shared__ float lds[CKK * SEG * 6 + 8];

    const int tid = threadIdx.x;
    const int blk = blockIdx.x;
    const int w0 = (blk & 7) * SEG;          // WW/SEG = 8
    const int h  = (blk >> 3) & (HH - 1);
    const int b  = blk >> 9;

    const float fb = (float)b, fh = (float)h, fw = (float)(w0 + tid);

    // ---- load this thread's full 24 B input group (all 3 channels) ----
    const float* g = in + ((b * HH + h) * WW + w0 + tid) * 6;
    const float2 v0 = ((const float2*)g)[0];   // c=0 (x,y)
    const float2 v1 = ((const float2*)g)[1];   // c=1
    const float2 v2 = ((const float2*)g)[2];   // c=2
    const float2 v[CKK] = {v0, v1, v2};

    // ---- compute, write vals, stage E rows [b,qx,qy,c,h,w] ----
    #pragma unroll
    for (int c = 0; c < CKK; ++c) {
        const float sx = v[c].x * 2.0f + 1.0f;
        const float sy = v[c].y * 2.0f + 81.0f;
        const float qx = (float)(int)sx;   // trunc == astype(int64), vals > 0
        const float qy = (float)(int)sy;
        const int nc = ((b * CKK + c) * HH + h) * WW + w0 + tid;
        out[6 * NN + nc] = 1.0f;                                  // presence_vals
        *(float2*)(out + 21 * NN + 2 * nc) = make_float2(sx, sy); // position_vals
        float2* e = (float2*)(lds + (c * SEG + tid) * 6);
        e[0] = make_float2(fb, qx);
        e[1] = make_float2(qy, (float)c);
        e[2] = make_float2(fh, fw);
    }
    __syncthreads();   // the only barrier

    // ---- drain presence_indices: staged layout IS the output layout ----
    #pragma unroll
    for (int c = 0; c < CKK; ++c) {
        const int ncBase = ((b * CKK + c) * HH + h) * WW + w0;
        const float4* src = (const float4*)(lds + c * SEG * 6);
        float4* dst = (float4*)(out + 6 * ncBase);                // 6*ncBase % 4 == 0
        #pragma unroll
        for (int i = tid; i < SEG * 6 / 4; i += 256)              // 384
            dst[i] = src[i];
    }

    // ---- drain position_indices: gather from E rows ----
    // chunk float f: n = f/14, k = f%14; val = E(n)[k mod 7], except
    // k==6 -> 0.0, k==13 -> 1.0. Only pat==12 wraps into row n+1 (cols 14,15
    // = next row's b, qx), and pat==12 never occurs at the last row.
    #pragma unroll
    for (int c = 0; c < CKK; ++c) {
        const int ncBase = ((b * CKK + c) * HH + h) * WW + w0;
        const float* src = lds + c * SEG * 6;
        float4* dst = (float4*)(out + 7 * NN + 14 * ncBase);      // 14*ncBase % 4 == 0
        #pragma unroll
        for (int i = tid; i < SEG * 14 / 4; i += 256) {           // 896
            const int gg = 4 * i;
            const int r1  = gg / 14;         // magic-mul, gg < 3584
            const int pat = gg - 14 * r1;    // even, 0..12
            float oe[4];
            #pragma unroll
            for (int e = 0; e < 4; ++e) {
                const int col  = pat + e;            // 0..15
                const int wrap = (col >= 14);        // row n+1
                const int k    = col - 14 * wrap;    // 0..13
                const int k7   = k - 7 * (k >= 7);   // 0..6
                const float lv = src[6 * (r1 + wrap) + k7];
                const float dv = (float)(k >= 7);    // d column: 0 or 1
                oe[e] = (k7 == 6) ? dv : lv;
            }
            dst[i] = make_float4(oe[0], oe[1], oe[2], oe[3]);
        }
    }
}

extern "C" void kernel_launch(void* const* d_in, const int* in_sizes, int n_in,
                              void* d_out, int out_size, void* d_ws, size_t ws_size,
                              hipStream_t stream) {
    const float* in = (const float*)d_in[0];
    float* out = (float*)d_out;
    ProjectBEV_kernel<<<NBLK, 256, 0, stream>>>(in, out);
}